// Round 4
// baseline (1208.043 us; speedup 1.0000x reference)
//
#include <hip/hip_runtime.h>

// AreaSelfAttention fused kernel for MI355X (gfx950).
// x:(4,256,252,252) fp32 -> pad to 256x256 -> 8x8 windows -> per-window
// q,k(32xP),v(256xP) 1x1 convs, S=q^T k, softmax rows, O=V P^T, out=gamma*O+x.
// R6: persistent blocks, 512 blocks x 512 thr (exactly 2/CU, whole grid
// resident), each sweeping 4 horizontally-consecutive window-PAIRS.
// T14 async-STAGE: each wave issues the NEXT pair's 16 global float4 loads
// right after staging its oacc (oacc dead -> 64 prefetch regs fit under the
// 128-reg budget); loads fly under the epilogue RMW. All in-loop barriers
// are lgkmcnt-only soft barriers (raw s_barrier) so the compiler's
// vmcnt(0)-drain-before-s_barrier doesn't kill the overlap (m97).
// R5 analysis: traffic near-compulsory, HBM duty only 33% from phase
// serialization -> this round attacks utilization, not bytes.
// Keeps: pair-width 64B-line global accesses, unfused phase 2 (R4 spill
// fix), XOR-swizzled LDS maps, transposed V GEMM, O-staged f32 epilogue.

#define HH 252
#define WW 252
#define CC 256
#define HW (HH * WW)

typedef __attribute__((ext_vector_type(8))) short bf8;     // 8 bf16 in 4 VGPRs
typedef __attribute__((ext_vector_type(4))) float f32x4;

__device__ __forceinline__ short f2bf(float f) {
    union { float f; unsigned u; } v; v.f = f;
    unsigned u = v.u;
    unsigned r = (u + 0x7fffu + ((u >> 16) & 1u)) >> 16;   // RNE
    return (short)r;
}

__device__ __forceinline__ unsigned pk2(float a, float b) {
    return (unsigned)(unsigned short)f2bf(a) |
           ((unsigned)(unsigned short)f2bf(b) << 16);
}

// Soft barrier: LDS-visibility only (lgkmcnt(0) + raw s_barrier), leaves
// global loads/stores in flight across it (unlike __syncthreads(), which
// hipcc lowers with a vmcnt(0) drain). sched_barrier(0) fences compiler
// reordering around the inline asm (rule #18 insurance).
__device__ __forceinline__ void soft_bar() {
    asm volatile("s_waitcnt lgkmcnt(0)" ::: "memory");
    __builtin_amdgcn_s_barrier();
    __builtin_amdgcn_sched_barrier(0);
}

// ---- LDS address maps (short indices, per 16384-short window region).
// XOR-swizzled on 8-short (16B) slots: MFMA fragment reads spread uniformly
// over the 8 16B bank-groups; writes stay b64-contiguous.
__device__ __forceinline__ int xaddr(int p, int c) {   // X^T [p=64][c=256]
    int slot = (c >> 3) ^ ((p & 7) ^ ((p >> 3) & 7));
    return p * 256 + (slot << 3) + (c & 7);
}
__device__ __forceinline__ int vaddr(int c, int p) {   // V [c=256][p=64]
    int slot = ((p >> 3) ^ (c & 7)) & 7;
    return c * 64 + (slot << 3) + (p & 7);
}
__device__ __forceinline__ int qaddr(int p, int cr) {  // q^T/k^T [p=64][cr=32]
    int slot = ((cr >> 3) ^ (p & 3)) & 3;
    return p * 32 + (slot << 3) + (cr & 7);
}
__device__ __forceinline__ int paddr(int i, int j) {   // P [i=64][j=64]
    int slot = ((j >> 3) ^ (i & 7)) & 7;
    return i * 64 + (slot << 3) + (j & 7);
}
// O staging (f32 [c=128][P=128]); XOR by 16 keeps float4 groups intact.
__device__ __forceinline__ int saddr(int c, int P) {
    return c * 128 + (P ^ ((c & 4) << 2));
}

// Wq (32x256), Wk (32x256), Wv (256x256) fp32 [o][c] -> bf16 MFMA A-frag
// order: frag (mt,kt), lane l, elem j -> W[mt*16+(l&15)][kt*32+(l>>4)*8+j]
// at ((mt*8+kt)*64+l)*8+j. WqF at 0, WkF at 8192, WvF at 16384. The
// B-fragment of W^T has identical per-lane indexing (transposed V GEMM).
__global__ __launch_bounds__(256) void prep_weights(
        const float* __restrict__ Wq, const float* __restrict__ Wk,
        const float* __restrict__ Wv, short* __restrict__ wf) {
    int t = blockIdx.x * 256 + threadIdx.x;
    if (t >= 81920) return;
    const float* W; int off, base;
    if (t < 8192)       { W = Wq; off = t;         base = 0; }
    else if (t < 16384) { W = Wk; off = t - 8192;  base = 8192; }
    else                { W = Wv; off = t - 16384; base = 16384; }
    int j = off & 7, l = (off >> 3) & 63, tile = off >> 9;
    int kt = tile & 7, mt = tile >> 3;
    int m = mt * 16 + (l & 15);
    int k = kt * 32 + ((l >> 4) * 8) + j;
    wf[base + off] = f2bf(W[m * 256 + k]);
}

__global__ __launch_bounds__(512, 4) void area_attn(
        const float* __restrict__ x, const short* __restrict__ wf,
        const float* __restrict__ bq, const float* __restrict__ bk,
        const float* __restrict__ bv, const float* __restrict__ gamma,
        float* __restrict__ out) {
    // LDS = 65536 + 16384 = 81920 B -> exactly 2 workgroups / CU (160 KiB).
    __shared__ __align__(16) short xs[32768]; // per-win 16384: X^T, then V;
                                              // f32 O-stage aliases all 64KB
    __shared__ __align__(16) short qk[8192];  // per-win 4096: qs|ks; ps alias

    const int tid  = threadIdx.x;
    const int lane = tid & 63, wv = tid >> 6;
    const int win  = wv >> 2, wvv = wv & 3;
    const int l15  = lane & 15, quad = lane >> 4;

    // Persistent mapping: xcd = bid&7 (HW round-robin). Each XCD owns the
    // grows with grow%8==xcd; a block sweeps 4 consecutive pair-columns of
    // one grow, so its own epilogues cover 256B contiguous per (c,h) row
    // (sector merge for the odd-h 16B-misaligned lines happens in-XCD).
    const int bid  = blockIdx.x;        // 0..511
    const int xcd  = bid & 7;
    const int idx  = bid >> 3;          // 0..63
    const int grow = (idx >> 2) * 8 + xcd;  // 0..127
    const int px0  = (idx & 3) * 4;     // first pair column of the sweep
    const int bimg = grow >> 5;
    const int ny   = grow & 31;
    const int hb   = ny * 8;
    const float* xb = x   + (size_t)bimg * CC * HW;
    float*       ob = out + (size_t)bimg * CC * HW;

    short* xsw = xs + win * 16384;
    short* qkw = qk + win * 4096;
    const f32x4 zero4 = {0.f, 0.f, 0.f, 0.f};

    // phase-1 thread geometry (fixed across the sweep)
    const int s1  = tid & 31, cg = tid >> 5;   // s1: h(3)|w4(2), cg: c/4
    const int hl  = s1 >> 2, w4 = s1 & 3;
    const int p0  = hl * 8 + (w4 & 1) * 4;
    const int hg  = hb + hl;
    short* dst1 = xs + (w4 >> 1) * 16384;
    const float* srcc = xb + (size_t)hg * WW + (size_t)cg * 4 * HW;

    float4 pf[16];                      // prefetch regs (statically indexed)
    auto issue_pref = [&](int tt) {
        int w0 = (px0 + tt) * 16 + w4 * 4;
        bool inb = (hg < HH) && (w0 < WW);   // edge float4s fully OOB, never partial
        const float* sp = srcc + w0;
        #pragma unroll
        for (int it = 0; it < 4; ++it)
            #pragma unroll
            for (int k = 0; k < 4; ++k)
                pf[it * 4 + k] = inb
                    ? *reinterpret_cast<const float4*>(sp + (size_t)(it * 64 + k) * HW)
                    : make_float4(0.f, 0.f, 0.f, 0.f);
    };

    issue_pref(0);
    const float g = gamma[0];

    #pragma unroll 1
    for (int t = 0; t < 4; ++t) {
        const int wb = (px0 + t) * 16;

        // ---- phase 1: pack prefetched regs -> LDS bf16 X^T[p][c] per window.
        // (compiler inserts the counted vmcnt wait on pf's loads here)
        #pragma unroll
        for (int it = 0; it < 4; ++it) {
            int c0 = it * 64 + cg * 4;
            #pragma unroll
            for (int i = 0; i < 4; ++i) {
                uint2 w2;
                w2.x = pk2(((const float*)&pf[it * 4 + 0])[i],
                           ((const float*)&pf[it * 4 + 1])[i]);
                w2.y = pk2(((const float*)&pf[it * 4 + 2])[i],
                           ((const float*)&pf[it * 4 + 3])[i]);
                *reinterpret_cast<uint2*>(&dst1[xaddr(p0 + i, c0)]) = w2;
            }
        }
        soft_bar();

        // ---- phase 2a: Q/K GEMM (per window). wvv 0,1 -> Q; 2,3 -> K.
        // X is the B-operand. Only 16 acc regs live (R4 spill fix: unfused).
        {
            const bool isK = (wvv >> 1) != 0;
            const int mt = wvv & 1;
            const short* WFqk = wf + (isK ? 8192 : 0);
            f32x4 qacc[4];
            #pragma unroll
            for (int nt = 0; nt < 4; ++nt) qacc[nt] = zero4;
            #pragma unroll
            for (int kt = 0; kt < 8; ++kt) {
                bf8 aw = *reinterpret_cast<const bf8*>(
                    WFqk + ((mt * 8 + kt) * 64 + lane) * 8);
                #pragma unroll
                for (int nt = 0; nt < 4; ++nt) {
                    bf8 b = *reinterpret_cast<const bf8*>(
                        &xsw[xaddr(nt * 16 + l15, kt * 32 + quad * 8)]);
                    qacc[nt] = __builtin_amdgcn_mfma_f32_16x16x32_bf16(
                        aw, b, qacc[nt], 0, 0, 0);
                }
            }
            int cb = mt * 16 + quad * 4;
            const float* bias = isK ? bk : bq;
            float bi0 = bias[cb + 0], bi1 = bias[cb + 1];
            float bi2 = bias[cb + 2], bi3 = bias[cb + 3];
            short* dst = isK ? (qkw + 2048) : qkw;
            #pragma unroll
            for (int nt = 0; nt < 4; ++nt) {
                int pos = nt * 16 + l15;
                uint2 w2;
                w2.x = pk2(qacc[nt][0] + bi0, qacc[nt][1] + bi1);
                w2.y = pk2(qacc[nt][2] + bi2, qacc[nt][3] + bi3);
                *reinterpret_cast<uint2*>(&dst[qaddr(pos, cb)]) = w2;
            }
        }

        // ---- phase 2b: transposed V GEMM  V^T[p][c] = X^T[p][cin]*Wv^T[cin][c]
        f32x4 vacc[4][4];                   // [p-tile][c-tile within wave]
        #pragma unroll
        for (int pt = 0; pt < 4; ++pt)
            #pragma unroll
            for (int ni = 0; ni < 4; ++ni) vacc[pt][ni] = zero4;
        #pragma unroll
        for (int kt = 0; kt < 8; ++kt) {
            bf8 xfr[4];
            #pragma unroll
            for (int pt = 0; pt < 4; ++pt)
                xfr[pt] = *reinterpret_cast<const bf8*>(
                    &xsw[xaddr(pt * 16 + l15, kt * 32 + quad * 8)]);
            #pragma unroll
            for (int ni = 0; ni < 4; ++ni) {
                bf8 bw = *reinterpret_cast<const bf8*>(
                    wf + 16384 + (((wvv * 4 + ni) * 8 + kt) * 64 + lane) * 8);
                #pragma unroll
                for (int pt = 0; pt < 4; ++pt)
                    vacc[pt][ni] = __builtin_amdgcn_mfma_f32_16x16x32_bf16(
                        xfr[pt], bw, vacc[pt][ni], 0, 0, 0);
            }
        }
        soft_bar();   // all X reads done; qs/ks visible to everyone

        // ---- write V (+bias, bf16) into xsw as V[c][p]: contiguous b64.
        #pragma unroll
        for (int ni = 0; ni < 4; ++ni) {
            int c = wvv * 64 + ni * 16 + l15;
            float bvc = bv[c];
            #pragma unroll
            for (int pt = 0; pt < 4; ++pt) {
                int p = pt * 16 + quad * 4;
                uint2 w2;
                w2.x = pk2(vacc[pt][ni][0] + bvc, vacc[pt][ni][1] + bvc);
                w2.y = pk2(vacc[pt][ni][2] + bvc, vacc[pt][ni][3] + bvc);
                *reinterpret_cast<uint2*>(&xsw[vaddr(c, p)]) = w2;
            }
        }
        // S-phase operands must be read BEFORE ps overwrites qs/ks (aliased).
        bf8 aq = *reinterpret_cast<const bf8*>(
            &qkw[qaddr(wvv * 16 + l15, quad * 8)]);
        bf8 kb8[4];
        #pragma unroll
        for (int nt = 0; nt < 4; ++nt)
            kb8[nt] = *reinterpret_cast<const bf8*>(
                &qkw[2048 + qaddr(nt * 16 + l15, quad * 8)]);
        soft_bar();   // qs/ks reads done -> ps may alias; V visible

        // ---- S = q^T k (M=i, N=j, K=32), softmax rows, P -> LDS bf16
        {
            f32x4 sacc[4];
            #pragma unroll
            for (int nt = 0; nt < 4; ++nt)
                sacc[nt] = __builtin_amdgcn_mfma_f32_16x16x32_bf16(
                    aq, kb8[nt], zero4, 0, 0, 0);
            #pragma unroll
            for (int r = 0; r < 4; ++r) {
                float mx = fmaxf(fmaxf(sacc[0][r], sacc[1][r]),
                                 fmaxf(sacc[2][r], sacc[3][r]));
                for (int m = 1; m < 16; m <<= 1) mx = fmaxf(mx, __shfl_xor(mx, m, 64));
                float e0 = __expf(sacc[0][r] - mx);
                float e1 = __expf(sacc[1][r] - mx);
                float e2 = __expf(sacc[2][r] - mx);
                float e3 = __expf(sacc[3][r] - mx);
                float sum = e0 + e1 + e2 + e3;
                for (int m = 1; m < 16; m <<= 1) sum += __shfl_xor(sum, m, 64);
                float inv = 1.f / sum;
                int i = wvv * 16 + quad * 4 + r;
                qkw[paddr(i,  0 + l15)] = f2bf(e0 * inv);
                qkw[paddr(i, 16 + l15)] = f2bf(e1 * inv);
                qkw[paddr(i, 32 + l15)] = f2bf(e2 * inv);
                qkw[paddr(i, 48 + l15)] = f2bf(e3 * inv);
            }
        }
        soft_bar();   // V + P ready

        // ---- O = V P^T (M=c 256, N=i 64, K=j 64). wave owns c [64wvv,+64).
        f32x4 oacc[4][4];
        #pragma unroll
        for (int mi = 0; mi < 4; ++mi)
            #pragma unroll
            for (int nt = 0; nt < 4; ++nt) oacc[mi][nt] = zero4;
        #pragma unroll
        for (int kt = 0; kt < 2; ++kt) {
            bf8 av[4], bp[4];
            #pragma unroll
            for (int mi = 0; mi < 4; ++mi)
                av[mi] = *reinterpret_cast<const bf8*>(
                    &xsw[vaddr((wvv * 4 + mi) * 16 + l15, kt * 32 + quad * 8)]);
            #pragma unroll
            for (int nt = 0; nt < 4; ++nt)
                bp[nt] = *reinterpret_cast<const bf8*>(
                    &qkw[paddr(nt * 16 + l15, kt * 32 + quad * 8)]);
            #pragma unroll
            for (int nt = 0; nt < 4; ++nt)
                #pragma unroll
                for (int mi = 0; mi < 4; ++mi)
                    oacc[mi][nt] = __builtin_amdgcn_mfma_f32_16x16x32_bf16(
                        av[mi], bp[nt], oacc[mi][nt], 0, 0, 0);
        }
        soft_bar();   // all V/P reads done -> xs reusable as f32 O-stage

        // ---- epilogue: stage O (f32) in xs, coalesced float4 RMW.
        // A wave's entire oacc is staged in ITS half -> right after staging,
        // oacc is dead and the wave issues the NEXT pair's prefetch (T14).
        float* st = (float*)xs;
        #pragma unroll
        for (int Hh = 0; Hh < 2; ++Hh) {
            if ((wvv >> 1) == Hh) {        // wave-uniform branch
                #pragma unroll
                for (int mi = 0; mi < 4; ++mi) {
                    int cl = (wvv & 1) * 64 + mi * 16 + quad * 4;
                    #pragma unroll
                    for (int nt = 0; nt < 4; ++nt) {
                        int P = win * 64 + nt * 16 + l15;
                        #pragma unroll
                        for (int r = 0; r < 4; ++r)
                            st[saddr(cl + r, P)] = oacc[mi][nt][r];
                    }
                }
                if (t < 3) issue_pref(t + 1);   // flies under the RMW loop
            }
            soft_bar();                    // half staged
            #pragma unroll
            for (int i = 0; i < 8; ++i) {
                int idx2 = i * 512 + tid;
                int c = idx2 >> 5, p4 = idx2 & 31;
                int P = p4 * 4;
                int wn = P >> 6, pos = P & 63;
                int hgg = hb + (pos >> 3), wg = wb + wn * 8 + (pos & 7);
                if (hgg < HH && wg < WW) { // edge float4s fully OOB, never partial
                    size_t o = (size_t)(Hh * 128 + c) * HW + (size_t)hgg * WW + wg;
                    float4 xv = *reinterpret_cast<const float4*>(xb + o);
                    f32x4 sv = *reinterpret_cast<const f32x4*>(&st[saddr(c, P)]);
                    float4 ov;
                    ov.x = g * sv[0] + xv.x;
                    ov.y = g * sv[1] + xv.y;
                    ov.z = g * sv[2] + xv.z;
                    ov.w = g * sv[3] + xv.w;
                    *reinterpret_cast<float4*>(ob + o) = ov;
                }
            }
            soft_bar();                    // half consumed; st reusable
        }
    }
}

extern "C" void kernel_launch(void* const* d_in, const int* in_sizes, int n_in,
                              void* d_out, int out_size, void* d_ws, size_t ws_size,
                              hipStream_t stream) {
    const float* x  = (const float*)d_in[0];
    const float* Wq = (const float*)d_in[1];
    const float* bq = (const float*)d_in[2];
    const float* Wk = (const float*)d_in[3];
    const float* bk = (const float*)d_in[4];
    const float* Wv = (const float*)d_in[5];
    const float* bv = (const float*)d_in[6];
    const float* gm = (const float*)d_in[7];
    short* wf = (short*)d_ws;   // 163840 B of bf16 weight fragments

    prep_weights<<<320, 256, 0, stream>>>(Wq, Wk, Wv, wf);
    area_attn<<<512, 512, 0, stream>>>(x, wf, bq, bk, bv, gm, (float*)d_out);
}